// Round 3
// baseline (337.795 us; speedup 1.0000x reference)
//
#include <hip/hip_runtime.h>
#include <hip/hip_fp16.h>

#define H_IMG 256
#define W_IMG 512
#define NPIX  (H_IMG*W_IMG)
#define BATCH 4
#define TS 16           // output tile side
#define EXT 22          // staged extent = TS + 2*3
#define NN  (EXT*EXT)   // 484
#define NSTR 66         // halfs per node (132 B = 33 dwords -> bank-spread)
#define LTH 256

// weights LDS layout (floats)
#define WL_WIN  0       // W_in [3][64]
#define WL_BIN  192     // b_in [64]
#define WL_BG   256     // bg   [3][64]
#define WL_WOUT 448     // W_out transposed [3][64]
#define WL_BOUT 640     // b_out[3]
#define WL_SZ   644

typedef _Float16 half8 __attribute__((ext_vector_type(8)));
typedef float v4f __attribute__((ext_vector_type(4)));

__device__ __forceinline__ float rs1(int v, int n) {
  return rsqrtf((float)(3 - (v==0) - (v==(n-1))));
}

__device__ __forceinline__ unsigned pack2(float a, float b) {
  __half2 h = __floats2half2_rn(a, b);
  return *reinterpret_cast<unsigned*>(&h);
}

// WgT[l][f][k] = fp16(Wg[l][k][f])
__global__ void k_wg(const float* __restrict__ Wg, __half* __restrict__ WgT) {
  int idx = blockIdx.x * 256 + threadIdx.x;      // 3*64*64 = 12288
  int l = idx >> 12, rem = idx & 4095;
  int f = rem >> 6, k = rem & 63;
  WgT[idx] = __float2half(Wg[(l << 12) + (k << 6) + f]);
}

__global__ __launch_bounds__(LTH, 2) void k_fused(
    const float* __restrict__ x, const __half* __restrict__ wgt,
    const float* __restrict__ W_in, const float* __restrict__ b_in,
    const float* __restrict__ bg, const float* __restrict__ W_out,
    const float* __restrict__ b_out, float* __restrict__ out) {
  __shared__ __half hs[NN * NSTR];   // 63,888 B
  __shared__ float wl[WL_SZ];
  const int tid = threadIdx.x;
  const int tx0 = blockIdx.x * TS, ty0 = blockIdx.y * TS;
  const int bb = blockIdx.z;

  if (tid < 192) wl[WL_WIN + tid] = W_in[tid];
  if (tid < 64)  wl[WL_BIN + tid] = b_in[tid];
  if (tid < 192) wl[WL_BG + tid]  = bg[tid];
  if (tid < 192) wl[WL_WOUT + tid] = W_out[(tid & 63) * 3 + (tid >> 6)];
  if (tid < 3)   wl[WL_BOUT + tid] = b_out[tid];
  __syncthreads();

  // ---- h0 staging ----
  const float* xb = x + (size_t)bb * 3 * NPIX;
#pragma unroll
  for (int p = 0; p < 2; ++p) {
    int n = tid + p * LTH;
    if (n < NN) {
      int r = n / EXT, c = n - r * EXT;
      int gy = ty0 - 3 + r, gx = tx0 - 3 + c;
      bool ok = (unsigned)gy < H_IMG && (unsigned)gx < W_IMG;
      __half* hp = &hs[n * NSTR];
      if (ok) {
        int gi = (gy << 9) + gx;
        float x0 = xb[gi], x1 = xb[NPIX + gi], x2 = xb[2 * NPIX + gi];
#pragma unroll
        for (int c8 = 0; c8 < 8; ++c8) {
          v4f w0a = *(const v4f*)&wl[WL_WIN +       c8*8], w0b = *(const v4f*)&wl[WL_WIN +       c8*8 + 4];
          v4f w1a = *(const v4f*)&wl[WL_WIN +  64 + c8*8], w1b = *(const v4f*)&wl[WL_WIN +  64 + c8*8 + 4];
          v4f w2a = *(const v4f*)&wl[WL_WIN + 128 + c8*8], w2b = *(const v4f*)&wl[WL_WIN + 128 + c8*8 + 4];
          v4f ba  = *(const v4f*)&wl[WL_BIN + c8*8],       bb2 = *(const v4f*)&wl[WL_BIN + c8*8 + 4];
          float rr[8];
#pragma unroll
          for (int k = 0; k < 4; ++k) {
            rr[k]   = ba[k]  + x0*w0a[k] + x1*w1a[k] + x2*w2a[k];
            rr[k+4] = bb2[k] + x0*w0b[k] + x1*w1b[k] + x2*w2b[k];
          }
          *(uint2*)(hp + c8*8)     = make_uint2(pack2(rr[0], rr[1]), pack2(rr[2], rr[3]));
          *(uint2*)(hp + c8*8 + 4) = make_uint2(pack2(rr[4], rr[5]), pack2(rr[6], rr[7]));
        }
      } else {
        uint2 z = make_uint2(0u, 0u);
#pragma unroll
        for (int c8 = 0; c8 < 8; ++c8) {
          *(uint2*)(hp + c8*8)     = z;
          *(uint2*)(hp + c8*8 + 4) = z;
        }
      }
    }
  }
  __syncthreads();

  const int l64 = tid & 63, lm = l64 & 15, lh = l64 >> 4, w = tid >> 6;

#pragma unroll
  for (int l = 0; l < 3; ++l) {
    const int OE = 20 - 2 * l;       // 20, 18, 16
    const int NO = OE * OE;
    const int NP = (OE / 2) * OE;    // 200, 162, 128

    half8 af0[4], af1[4]; v4f cbv[4];
#pragma unroll
    for (int ft = 0; ft < 4; ++ft) {
      const __half* wp = wgt + l * 4096 + (ft * 16 + lm) * 64 + lh * 8;
      af0[ft] = *(const half8*)wp;
      af1[ft] = *(const half8*)(wp + 32);
      cbv[ft] = *(const v4f*)&wl[WL_BG + l * 64 + ft * 16 + lh * 4];
    }

    uint2 stL[2][8], stR[2][8];
    const bool act = tid < NP;
    int br = 0, bc = 0;
    if (act) {
      int pr = tid / (OE / 2), pc2 = tid - pr * (OE / 2);
      br = pr + l + 1; bc = 2 * pc2 + l + 1;
      int gy = ty0 - 3 + br, gx = tx0 - 3 + bc;
      float ry[3] = {rs1(gy-1, H_IMG), rs1(gy, H_IMG), rs1(gy+1, H_IMG)};
      float rx[4] = {rs1(gx-1, W_IMG), rs1(gx, W_IMG), rs1(gx+1, W_IMG), rs1(gx+2, W_IMG)};
      float dL = ry[1] * rx[1], dR = ry[1] * rx[2];
      float scL[9], scR[9];
#pragma unroll
      for (int j = 0; j < 3; ++j)
#pragma unroll
        for (int i = 0; i < 3; ++i) {
          scL[j*3+i] = dL * ry[j] * rx[i];
          scR[j*3+i] = dR * ry[j] * rx[i+1];
        }
      const __half* base = &hs[((br - 1) * EXT + (bc - 1)) * NSTR];
#pragma unroll
      for (int c8 = 0; c8 < 8; ++c8) {
        float aL[8] = {0,0,0,0,0,0,0,0}, aR[8] = {0,0,0,0,0,0,0,0};
#pragma unroll
        for (int j = 0; j < 3; ++j) {
          const __half* hp = base + j * (EXT * NSTR) + c8 * 8;
          half8 v0 = *(const half8*)hp;
          half8 v1 = *(const half8*)(hp + NSTR);
          half8 v2 = *(const half8*)(hp + 2 * NSTR);
          half8 v3 = *(const half8*)(hp + 3 * NSTR);
#pragma unroll
          for (int k = 0; k < 8; ++k) {
            aL[k] = fmaf((float)v0[k], scL[j*3+0], aL[k]);
            aL[k] = fmaf((float)v1[k], scL[j*3+1], aL[k]);
            aL[k] = fmaf((float)v2[k], scL[j*3+2], aL[k]);
            aR[k] = fmaf((float)v1[k], scR[j*3+0], aR[k]);
            aR[k] = fmaf((float)v2[k], scR[j*3+1], aR[k]);
            aR[k] = fmaf((float)v3[k], scR[j*3+2], aR[k]);
          }
        }
        stL[0][c8] = make_uint2(pack2(aL[0],aL[1]), pack2(aL[2],aL[3]));
        stL[1][c8] = make_uint2(pack2(aL[4],aL[5]), pack2(aL[6],aL[7]));
        stR[0][c8] = make_uint2(pack2(aR[0],aR[1]), pack2(aR[2],aR[3]));
        stR[1][c8] = make_uint2(pack2(aR[4],aR[5]), pack2(aR[6],aR[7]));
      }
    }
    __syncthreads();
    if (act) {
      __half* d0 = &hs[(br * EXT + bc) * NSTR];
#pragma unroll
      for (int c8 = 0; c8 < 8; ++c8) {
        *(uint2*)(d0 + c8*8)            = stL[0][c8];
        *(uint2*)(d0 + c8*8 + 4)        = stL[1][c8];
        *(uint2*)(d0 + NSTR + c8*8)     = stR[0][c8];
        *(uint2*)(d0 + NSTR + c8*8 + 4) = stR[1][c8];
      }
    }
    __syncthreads();

    for (int g = w; g * 16 < NO; g += 4) {
      int n = g * 16 + lm;
      int r = n / OE, c = n - r * OE;
      int bidx = (r + l + 1) * EXT + (c + l + 1);
      const __half* sp = &hs[bidx * NSTR + lh * 8];
      half8 bf0 = *(const half8*)sp;
      half8 bf1 = *(const half8*)(sp + 32);
      v4f d[4];
#pragma unroll
      for (int ft = 0; ft < 4; ++ft) {
        v4f t = __builtin_amdgcn_mfma_f32_16x16x32_f16(af0[ft], bf0, cbv[ft], 0, 0, 0);
        d[ft]  = __builtin_amdgcn_mfma_f32_16x16x32_f16(af1[ft], bf1, t, 0, 0, 0);
      }
      if (n < NO) {
        int gy = ty0 - 3 + (r + l + 1), gx = tx0 - 3 + (c + l + 1);
        bool ok = (unsigned)gy < H_IMG && (unsigned)gx < W_IMG;
        __half* hp = &hs[bidx * NSTR + lh * 4];
#pragma unroll
        for (int ft = 0; ft < 4; ++ft) {
          float e0 = ok ? fmaxf(d[ft][0], 0.f) : 0.f;
          float e1 = ok ? fmaxf(d[ft][1], 0.f) : 0.f;
          float e2 = ok ? fmaxf(d[ft][2], 0.f) : 0.f;
          float e3 = ok ? fmaxf(d[ft][3], 0.f) : 0.f;
          *(uint2*)(hp + ft * 16) = make_uint2(pack2(e0, e1), pack2(e2, e3));
        }
      }
    }
    __syncthreads();
  }

  // ---- epilogue ----
  {
    int r = tid >> 4, c = tid & 15;
    int bidx = (r + 3) * EXT + (c + 3);
    const __half* hp = &hs[bidx * NSTR];
    float p0 = wl[WL_BOUT + 0], p1 = wl[WL_BOUT + 1], p2 = wl[WL_BOUT + 2];
#pragma unroll
    for (int c8 = 0; c8 < 8; ++c8) {
      half8 v = *(const half8*)(hp + c8 * 8);
      v4f w0a = *(const v4f*)&wl[WL_WOUT +       c8*8], w0b = *(const v4f*)&wl[WL_WOUT +       c8*8 + 4];
      v4f w1a = *(const v4f*)&wl[WL_WOUT +  64 + c8*8], w1b = *(const v4f*)&wl[WL_WOUT +  64 + c8*8 + 4];
      v4f w2a = *(const v4f*)&wl[WL_WOUT + 128 + c8*8], w2b = *(const v4f*)&wl[WL_WOUT + 128 + c8*8 + 4];
#pragma unroll
      for (int k = 0; k < 4; ++k) {
        float fa = (float)v[k], fb = (float)v[k + 4];
        p0 = fmaf(fa, w0a[k], p0); p0 = fmaf(fb, w0b[k], p0);
        p1 = fmaf(fa, w1a[k], p1); p1 = fmaf(fb, w1b[k], p1);
        p2 = fmaf(fa, w2a[k], p2); p2 = fmaf(fb, w2b[k], p2);
      }
    }
    int gi = ((ty0 + r) << 9) + (tx0 + c);
    float* ob = out + (size_t)bb * 3 * NPIX;
    ob[gi] = p0; ob[NPIX + gi] = p1; ob[2 * NPIX + gi] = p2;
  }
}

extern "C" void kernel_launch(void* const* d_in, const int* in_sizes, int n_in,
                              void* d_out, int out_size, void* d_ws, size_t ws_size,
                              hipStream_t stream) {
  const float* x     = (const float*)d_in[0];
  const float* W_in  = (const float*)d_in[3];
  const float* b_in  = (const float*)d_in[4];
  const float* Wg    = (const float*)d_in[5];
  const float* bg    = (const float*)d_in[6];
  const float* W_out = (const float*)d_in[7];
  const float* b_out = (const float*)d_in[8];
  float* out = (float*)d_out;

  __half* WgT = (__half*)d_ws;   // 24 KiB scratch

  k_wg<<<dim3(48), 256, 0, stream>>>(Wg, WgT);
  dim3 grid(W_IMG / TS, H_IMG / TS, BATCH);   // 32 x 16 x 4
  k_fused<<<grid, LTH, 0, stream>>>(x, WgT, W_in, b_in, bg, W_out, b_out, out);
}

// Round 4
// 275.328 us; speedup vs baseline: 1.2269x; 1.2269x over previous
//
#include <hip/hip_runtime.h>
#include <hip/hip_fp16.h>

#define H_IMG 256
#define W_IMG 512
#define NPIX  (H_IMG*W_IMG)
#define BATCH 4
#define TSX 16
#define TSY 8
#define HXX 18          // TSX+2
#define HYY 10          // TSY+2
#define HN  180         // HXX*HYY
#define SSTR 72         // halfs per node (144 B -> 2-way-free banking for b128)
#define NTH 128

typedef _Float16 half8 __attribute__((ext_vector_type(8)));
typedef float v4f __attribute__((ext_vector_type(4)));

__device__ __forceinline__ float rs1(int v, int n){ return rsqrtf((float)(3-(v==0)-(v==(n-1)))); }
__device__ __forceinline__ unsigned pack2(float a, float b){ __half2 h=__floats2half2_rn(a,b); return *reinterpret_cast<unsigned*>(&h); }

// Prep into d_out head: WgT[l][f][k] fp16 (12288) + WoT[c][f] fp16 (192)
__global__ void k_prep(const float* __restrict__ Wg, const float* __restrict__ W_out,
                       __half* __restrict__ dst){
  int idx = blockIdx.x*256 + threadIdx.x;
  if (idx < 12288){
    int l = idx>>12, rem = idx&4095, f = rem>>6, k = rem&63;
    dst[idx] = __float2half(Wg[(l<<12)+(k<<6)+f]);
  } else if (idx < 12480){
    int i = idx-12288, c = i>>6, f = i&63;
    dst[idx] = __float2half(W_out[f*3+c]);
  }
}

// Copy layer-2 WgT slice + WoT (4288 halfs) from d_out head into ws (h1 region, dead)
__global__ void k_prep2(const __half* __restrict__ src, __half* __restrict__ dst){
  int idx = blockIdx.x*256 + threadIdx.x;
  if (idx < 4288) dst[idx] = src[idx];
}

// MODE 0: stage h0 from x via MFMA, output h1 to global
// MODE 1: stage halo from hin,      output h2 to global
// MODE 2: stage halo from hin,      fused out-projection, output fp32 out
template<int MODE>
__global__ __launch_bounds__(NTH, 3) void k_gcn(
    const float* __restrict__ x, const __half* __restrict__ hin,
    const __half* __restrict__ wgt, const float* __restrict__ bgl,
    const float* __restrict__ W_in, const float* __restrict__ b_in,
    const __half* __restrict__ wot, const float* __restrict__ b_out,
    __half* __restrict__ hout, float* __restrict__ outp)
{
  __shared__ __half hs[HN * SSTR];   // 25,920 B -> 6 blocks/CU
  const int tid = threadIdx.x;
  const int tx0 = blockIdx.x * TSX, ty0 = blockIdx.y * TSY;
  const int bb  = blockIdx.z;
  const int l64 = tid & 63, lm = l64 & 15, lh = l64 >> 4, w = tid >> 6;

  // layer-GEMM A-fragments (WgT) + bias (L2-hot)
  half8 af0[4], af1[4]; v4f cbv[4];
#pragma unroll
  for (int ft = 0; ft < 4; ++ft){
    const __half* wp = wgt + (ft*16 + lm)*64 + lh*8;
    af0[ft] = *(const half8*)wp;
    af1[ft] = *(const half8*)(wp + 32);
    cbv[ft] = *(const v4f*)(bgl + ft*16 + lh*4);
  }

  if (MODE == 0){
    // ---- h0 halo built in LDS via MFMA: D[f][node] = W_inT x xcols + b_in ----
    half8 aq[4]; v4f cbi[4];
#pragma unroll
    for (int ft = 0; ft < 4; ++ft){
      half8 a = (half8)0;
      if (lh == 0){
        a[0] = (_Float16)W_in[       ft*16 + lm];
        a[1] = (_Float16)W_in[ 64 +  ft*16 + lm];
        a[2] = (_Float16)W_in[128 +  ft*16 + lm];
      }
      aq[ft] = a;
      cbi[ft] = *(const v4f*)(b_in + ft*16 + lh*4);
    }
    const float* xb = x + (size_t)bb*3*NPIX;
    for (int gh = w; gh < 12; gh += 2){      // wave-uniform trip; only gh=11 has tail lanes
      int hn = gh*16 + lm;
      int row = hn / HXX, col = hn - row*HXX;
      int gy = ty0 - 1 + row, gx = tx0 - 1 + col;
      bool inim = ((unsigned)gy < H_IMG) && ((unsigned)gx < W_IMG) && (hn < HN);
      float x0=0.f, x1=0.f, x2=0.f;
      if (inim && lh == 0){
        int gi = (gy<<9) + gx;
        x0 = xb[gi]; x1 = xb[NPIX+gi]; x2 = xb[2*NPIX+gi];
      }
      half8 bq = (half8)0;
      bq[0] = (_Float16)x0; bq[1] = (_Float16)x1; bq[2] = (_Float16)x2;
      v4f d[4];
#pragma unroll
      for (int ft = 0; ft < 4; ++ft)
        d[ft] = __builtin_amdgcn_mfma_f32_16x16x32_f16(aq[ft], bq, cbi[ft], 0,0,0);
      if (hn < HN){                          // OOB-image nodes must be ZERO (not bias)
        __half* hp = &hs[hn*SSTR + lh*4];
#pragma unroll
        for (int ft = 0; ft < 4; ++ft){
          float e0 = inim ? d[ft][0] : 0.f, e1 = inim ? d[ft][1] : 0.f;
          float e2 = inim ? d[ft][2] : 0.f, e3 = inim ? d[ft][3] : 0.f;
          *(uint2*)(hp + ft*16) = make_uint2(pack2(e0,e1), pack2(e2,e3));
        }
      }
    }
  } else {
    // ---- stage halo tile from hin (fp16), OOB -> 0 ----
    const __half* hb = hin + (size_t)bb*NPIX*64;
#pragma unroll
    for (int p = 0; p < 12; ++p){
      int it = tid + p*NTH;
      if (it < HN*8){
        int c8 = it & 7, hn = it >> 3;
        int row = hn / HXX, col = hn - row*HXX;
        int gy = ty0 - 1 + row, gx = tx0 - 1 + col;
        uint4 v = make_uint4(0u,0u,0u,0u);
        if ((unsigned)gy < H_IMG && (unsigned)gx < W_IMG)
          v = *(const uint4*)(hb + ((size_t)((gy<<9)+gx))*64 + (c8<<3));
        *(uint4*)&hs[hn*SSTR + (c8<<3)] = v;
      }
    }
  }
  __syncthreads();

  // ---- separable stencil, column-rolling: tmp = Sx-pass (f32 regs), s = Sy-pass ----
  const int cx = tid & 15;        // output column
  const int c8 = tid >> 4;        // channel octet
  const int gxc = tx0 + cx;
  const float rxm = rs1(gxc-1, W_IMG), rxc = rs1(gxc, W_IMG), rxp = rs1(gxc+1, W_IMG);
  const float cxm = rxc*rxm, cxc = rxc*rxc, cxp = rxc*rxp;
  float ryv[HYY];
#pragma unroll
  for (int y = 0; y < HYY; ++y) ryv[y] = rs1(ty0 - 1 + y, H_IMG);

  v4f t0a = (v4f)0, t0b = (v4f)0, t1a = (v4f)0, t1b = (v4f)0;
  uint4 sreg[TSY];
#pragma unroll
  for (int y = 0; y < HYY; ++y){
    const __half* hp = &hs[(y*HXX + cx)*SSTR + c8*8];
    half8 vL = *(const half8*)hp;
    half8 vC = *(const half8*)(hp + SSTR);
    half8 vR = *(const half8*)(hp + 2*SSTR);
    v4f na, nb;
#pragma unroll
    for (int k = 0; k < 4; ++k){
      na[k] = fmaf(cxp,(float)vR[k],   fmaf(cxc,(float)vC[k],   cxm*(float)vL[k]));
      nb[k] = fmaf(cxp,(float)vR[k+4], fmaf(cxc,(float)vC[k+4], cxm*(float)vL[k+4]));
    }
    if (y >= 2){
      const int yo = y - 2;
      const float am = ryv[yo+1]*ryv[yo], ac = ryv[yo+1]*ryv[yo+1], ap = ryv[yo+1]*ryv[yo+2];
      v4f sa, sb;
#pragma unroll
      for (int k = 0; k < 4; ++k){
        sa[k] = fmaf(ap, na[k], fmaf(ac, t1a[k], am*t0a[k]));
        sb[k] = fmaf(ap, nb[k], fmaf(ac, t1b[k], am*t0b[k]));
      }
      sreg[yo] = make_uint4(pack2(sa[0],sa[1]), pack2(sa[2],sa[3]),
                            pack2(sb[0],sb[1]), pack2(sb[2],sb[3]));
    }
    t0a = t1a; t0b = t1b; t1a = na; t1b = nb;
  }
  __syncthreads();                 // all halo reads done; safe to overwrite
#pragma unroll
  for (int yo = 0; yo < TSY; ++yo)
    *(uint4*)&hs[(yo*16 + cx)*SSTR + c8*8] = sreg[yo];
  __syncthreads();

  // ---- MODE 2 epilogue weights (after sreg dies; keeps VGPR peak down) ----
  _Float16 wv0[16], wv1[16], wv2[16];
  float bo0 = 0.f, bo1 = 0.f, bo2 = 0.f;
  if (MODE == 2){
#pragma unroll
    for (int ft = 0; ft < 4; ++ft){
      *(uint2*)&wv0[ft*4] = *(const uint2*)(wot +        ft*16 + lh*4);
      *(uint2*)&wv1[ft*4] = *(const uint2*)(wot +  64 +  ft*16 + lh*4);
      *(uint2*)&wv2[ft*4] = *(const uint2*)(wot + 128 +  ft*16 + lh*4);
    }
    bo0 = b_out[0]; bo1 = b_out[1]; bo2 = b_out[2];
  }

  // ---- GEMM: D[f][node] = WgT x s^T + bg, one row-group of 16 nodes per iter ----
  __half* hb_out = hout + (size_t)bb*NPIX*64;   // unused in MODE 2
  float*  ob = outp + (size_t)bb*3*NPIX;        // unused in MODE 0/1
#pragma unroll
  for (int i = 0; i < 4; ++i){
    const int g = w*4 + i;
    const __half* sp = &hs[(g*16 + lm)*SSTR + lh*8];
    half8 b0 = *(const half8*)sp;
    half8 b1 = *(const half8*)(sp + 32);
    v4f d[4];
#pragma unroll
    for (int ft = 0; ft < 4; ++ft){
      v4f t = __builtin_amdgcn_mfma_f32_16x16x32_f16(af0[ft], b0, cbv[ft], 0,0,0);
      d[ft]  = __builtin_amdgcn_mfma_f32_16x16x32_f16(af1[ft], b1, t, 0,0,0);
    }
    const int gi = ((ty0 + g) << 9) + tx0 + lm;
    if (MODE != 2){
      __half* hp = hb_out + (size_t)gi*64 + lh*4;
#pragma unroll
      for (int ft = 0; ft < 4; ++ft){
        float e0 = fmaxf(d[ft][0],0.f), e1 = fmaxf(d[ft][1],0.f);
        float e2 = fmaxf(d[ft][2],0.f), e3 = fmaxf(d[ft][3],0.f);
        *(uint2*)(hp + ft*16) = make_uint2(pack2(e0,e1), pack2(e2,e3));
      }
    } else {
      float p0=0.f, p1=0.f, p2=0.f;
#pragma unroll
      for (int ft = 0; ft < 4; ++ft){
#pragma unroll
        for (int r = 0; r < 4; ++r){
          float e = fmaxf(d[ft][r], 0.f);
          p0 = fmaf(e, (float)wv0[ft*4+r], p0);
          p1 = fmaf(e, (float)wv1[ft*4+r], p1);
          p2 = fmaf(e, (float)wv2[ft*4+r], p2);
        }
      }
      p0 += __shfl_xor(p0, 16); p0 += __shfl_xor(p0, 32);
      p1 += __shfl_xor(p1, 16); p1 += __shfl_xor(p1, 32);
      p2 += __shfl_xor(p2, 16); p2 += __shfl_xor(p2, 32);
      if (lh == 0){
        ob[gi] = p0 + bo0; ob[NPIX + gi] = p1 + bo1; ob[2*NPIX + gi] = p2 + bo2;
      }
    }
  }
}

extern "C" void kernel_launch(void* const* d_in, const int* in_sizes, int n_in,
                              void* d_out, int out_size, void* d_ws, size_t ws_size,
                              hipStream_t stream) {
  const float* x     = (const float*)d_in[0];
  // d_in[1]=src, d_in[2]=dst — unused (analytic grid topology)
  const float* W_in  = (const float*)d_in[3];
  const float* b_in  = (const float*)d_in[4];
  const float* Wg    = (const float*)d_in[5];
  const float* bg    = (const float*)d_in[6];
  const float* W_out = (const float*)d_in[7];
  const float* b_out = (const float*)d_in[8];
  float* out = (float*)d_out;

  // Weight scratch lives in d_out head (rewritten every call; final kernel
  // reads weights only from ws, so it can overwrite d_out freely).
  __half* WgT = (__half*)d_out;                     // 12480 halfs = 24,960 B
  __half* h1  = (__half*)d_ws;                      // 67.1 MB
  __half* h2  = h1 + (size_t)BATCH*NPIX*64;         // 67.1 MB
  __half* w2c = h1;                                 // layer-2 weights, after h1 dies

  k_prep<<<dim3(49), 256, 0, stream>>>(Wg, W_out, WgT);

  dim3 grid(W_IMG/TSX, H_IMG/TSY, BATCH);           // 32 x 32 x 4 = 4096 blocks
  k_gcn<0><<<grid, NTH, 0, stream>>>(x, nullptr, WgT,        bg,      W_in, b_in,
                                     nullptr, nullptr, h1, nullptr);
  k_gcn<1><<<grid, NTH, 0, stream>>>(nullptr, h1, WgT + 4096, bg + 64, nullptr, nullptr,
                                     nullptr, nullptr, h2, nullptr);
  k_prep2<<<dim3(17), 256, 0, stream>>>(WgT + 8192, w2c);
  k_gcn<2><<<grid, NTH, 0, stream>>>(nullptr, h2, w2c,        bg + 128, nullptr, nullptr,
                                     w2c + 4096, b_out, nullptr, out);
}